// Round 12
// baseline (149.502 us; speedup 1.0000x reference)
//
#include <hip/hip_runtime.h>
#include <hip/hip_bf16.h>
#include <math.h>

#define NB 8
#define NC 256
#define NHW 2304
#define NH 4
#define HD 64
#define CPG 8
#define GN_EPS 1e-5f

typedef __bf16 bf16;
typedef __bf16 bf16x4 __attribute__((ext_vector_type(4)));
typedef __bf16 bf16x8 __attribute__((ext_vector_type(8)));
typedef float f32x4 __attribute__((ext_vector_type(4)));
typedef float f32x16 __attribute__((ext_vector_type(16)));
typedef int i32x4 __attribute__((ext_vector_type(4)));
typedef unsigned int u32;

#define MFMA16(a, b, c) __builtin_amdgcn_mfma_f32_16x16x32_bf16(a, b, c, 0, 0, 0)
#define MFMA32(a, b, c) __builtin_amdgcn_mfma_f32_32x32x16_bf16(a, b, c, 0, 0, 0)

// fast 2^x: raw v_exp_f32 (exact for our |x| <~ 40 range)
__device__ __forceinline__ float fexp2(float x) {
  float r;
  asm("v_exp_f32 %0, %1" : "=v"(r) : "v"(x));
  return r;
}

// ---------------- fused: weight fp32->bf16 (blocks 0..767) + GroupNorm ------
// GN single-pass: block = (b,g); thread holds its 8ch x 9pos slice (72 f32)
// in registers -> x read ONCE.
__global__ __launch_bounds__(256) void k_pre(const float* __restrict__ x,
                                             const float* __restrict__ gw,
                                             const float* __restrict__ gb,
                                             const float* __restrict__ qw,
                                             const float* __restrict__ pw,
                                             bf16* __restrict__ xnt,
                                             bf16* __restrict__ wq,
                                             bf16* __restrict__ wp) {
  int t = threadIdx.x;
  if (blockIdx.x < 768) {
    int i = blockIdx.x * 256 + t;
    wq[i] = (bf16)qw[i];
    if (i < NC * NC) wp[i] = (bf16)pw[i];
    return;
  }
  int bid = blockIdx.x - 768;
  int b = bid >> 5;
  int g = bid & 31;
  int c0 = g * CPG;
  const float* xb = x + (b * NC + c0) * NHW;
  float v[CPG][9];
  float s = 0.f, s2 = 0.f;
#pragma unroll
  for (int cc = 0; cc < CPG; ++cc)
#pragma unroll
    for (int k = 0; k < 9; ++k) {
      float val = xb[cc * NHW + k * 256 + t];
      v[cc][k] = val;
      s += val;
      s2 += val * val;
    }
#pragma unroll
  for (int m = 1; m < 64; m <<= 1) {
    s += __shfl_xor(s, m);
    s2 += __shfl_xor(s2, m);
  }
  __shared__ float red[8];
  int wid = t >> 6;
  if ((t & 63) == 0) { red[wid] = s; red[4 + wid] = s2; }
  __syncthreads();
  s = red[0] + red[1] + red[2] + red[3];
  s2 = red[4] + red[5] + red[6] + red[7];
  const float inv_n = 1.0f / (CPG * NHW);
  float mean = s * inv_n;
  float var = s2 * inv_n - mean * mean;
  float rsq = rsqrtf(var + GN_EPS);
  float ka[CPG], kb[CPG];
#pragma unroll
  for (int cc = 0; cc < CPG; ++cc) {
    float wv = gw[c0 + cc];
    ka[cc] = wv * rsq;
    kb[cc] = gb[c0 + cc] - mean * rsq * wv;
  }
  bf16* dst = xnt + b * NHW * NC + c0;
#pragma unroll
  for (int k = 0; k < 9; ++k) {
    bf16x8 o;
#pragma unroll
    for (int cc = 0; cc < CPG; ++cc)
      o[cc] = (bf16)(v[cc][k] * ka[cc] + kb[cc]);
    *reinterpret_cast<bf16x8*>(dst + (k * 256 + t) * NC) = o;
  }
}

// ---------------- QKV GEMM: M=hw(i), N=768(o), K=256(c) ----------------
__global__ __launch_bounds__(256) void k_qkv(const bf16* __restrict__ xnt,
                                             const bf16* __restrict__ wq,
                                             const float* __restrict__ qkvb,
                                             bf16* __restrict__ qt,
                                             bf16* __restrict__ kt,
                                             bf16* __restrict__ vv) {
  int b = blockIdx.z;
  int i_base = blockIdx.x * 128;
  int o_base = blockIdx.y * 128;
  int t = threadIdx.x;
  int lane = t & 63, wid = t >> 6;
  int wm = (wid >> 1) * 64, wn = (wid & 1) * 64;
  int l15 = lane & 15, g = lane >> 4;
  const bool qk = (o_base < 512);
  const bf16* ab;
  const bf16* bb;
  if (qk) {
    ab = wq + (o_base + wm + l15) * NC + g * 8;
    bb = xnt + ((size_t)b * NHW + i_base + wn + l15) * NC + g * 8;
  } else {
    ab = xnt + ((size_t)b * NHW + i_base + wm + l15) * NC + g * 8;
    bb = wq + (o_base + wn + l15) * NC + g * 8;
  }
  f32x4 acc[4][4] = {};
#pragma unroll 2
  for (int kc = 0; kc < 8; ++kc) {
    bf16x8 af[4], bf[4];
#pragma unroll
    for (int mf = 0; mf < 4; ++mf)
      af[mf] = *reinterpret_cast<const bf16x8*>(ab + mf * 16 * NC + kc * 32);
#pragma unroll
    for (int nf = 0; nf < 4; ++nf)
      bf[nf] = *reinterpret_cast<const bf16x8*>(bb + nf * 16 * NC + kc * 32);
#pragma unroll
    for (int mf = 0; mf < 4; ++mf)
#pragma unroll
      for (int nf = 0; nf < 4; ++nf)
        acc[mf][nf] = MFMA16(af[mf], bf[nf], acc[mf][nf]);
  }
  if (qk) {
    const float qscale = 0.125f * 1.4426950408889634f;
#pragma unroll
    for (int mf = 0; mf < 4; ++mf) {
      int o0 = o_base + wm + mf * 16 + g * 4;  // rows o0..o0+3
      f32x4 b4 = *reinterpret_cast<const f32x4*>(qkvb + o0);
      bool isQ = (o0 < 256);
      float sc = isQ ? qscale : 1.0f;
      int oo = isQ ? o0 : o0 - 256;
      bf16* base = (isQ ? qt : kt) +
                   ((size_t)(b * NH + (oo >> 6)) * NHW) * HD + (oo & 63);
#pragma unroll
      for (int nf = 0; nf < 4; ++nf) {
        int i = i_base + wn + nf * 16 + l15;
        bf16x4 w;
#pragma unroll
        for (int r = 0; r < 4; ++r)
          w[r] = (bf16)((acc[mf][nf][r] + b4[r]) * sc);
        *reinterpret_cast<bf16x4*>(base + (size_t)i * HD) = w;
      }
    }
  } else {
#pragma unroll
    for (int nf = 0; nf < 4; ++nf) {
      int og = o_base + wn + nf * 16 + l15;  // 512..767
      float bias = qkvb[og];
      int o2 = og - 512;
      bf16* dp = vv + ((size_t)(b * NH + (o2 >> 6)) * HD + (o2 & 63)) * NHW +
                 i_base + wm + g * 4;
#pragma unroll
      for (int mf = 0; mf < 4; ++mf) {
        bf16x4 w;
#pragma unroll
        for (int r = 0; r < 4; ++r) w[r] = (bf16)(acc[mf][nf][r] + bias);
        *reinterpret_cast<bf16x4*>(dp + mf * 16) = w;
      }
    }
  }
}

// ---------------- flash attention: rotated pipeline (T15) --------------------
// r11 base + 1-tile software rotation: iteration t runs softmax(t-1) [VALU],
// QK(t) [matrix] and PV(t-1) [matrix] — three mutually independent chains the
// scheduler interleaves, instead of the serial QK->SM->PV chain. V staging
// LAGS K by one tile (kbuf holds t, vbuf holds t-1) so PV(t-1) reads V from
// LDS directly — no V reg double-buffer. One barrier/tile as before.
// LDS layout: elem(c,row) = c*512 + ((row+c)&63)*8 (conflict-free b128).
// launch_bounds(256,3): VGPR headroom for the extra live s-state (no spill).
__global__ __launch_bounds__(256, 3) void k_attn(const bf16* __restrict__ qt,
                                                 const bf16* __restrict__ kt,
                                                 const bf16* __restrict__ vv,
                                                 bf16* __restrict__ att) {
  __shared__ union SM {
    struct { bf16 k[2][4096]; bf16 v[2][4096]; } kv;
    float m[2][64][33];
  } smem;

  const int tid = threadIdx.x;
  const int wid = tid >> 6, lane = tid & 63;
  const int l31 = lane & 31, g2 = lane >> 5;
  const int ig = wid & 1, jsub = wid >> 1;

  // bijective XCD swizzle: 1152 blocks = 8 XCD x 144; each XCD gets 4 heads
  const int bid = blockIdx.x;
  const int wg = (bid & 7) * 144 + (bid >> 3);
  const int bh = wg / 36, it = wg % 36;
  const int b = bh >> 2, n = bh & 3;
  const int i0w = it * 64 + ig * 32;

  const bf16* qb = qt + (size_t)bh * NHW * HD;
  const bf16* kb = kt + (size_t)bh * NHW * HD;
  const bf16* vb = vv + (size_t)bh * HD * NHW;

  // staging: thread (r0 = row 0..31, cs = 16B-chunk 0..7); rows r0 and r0+32
  const int r0 = tid >> 3, cs = tid & 7;
  const bf16* kg0 = kb + r0 * HD + cs * 8;
  const bf16* kg1 = kb + (r0 + 32) * HD + cs * 8;
  const bf16* vg0 = vb + (size_t)r0 * NHW + cs * 8;
  const bf16* vg1 = vb + (size_t)(r0 + 32) * NHW + cs * 8;
#define EOFF(c, row) ((c) * 512 + ((((row) + (c)) & 63) << 3))
  const int lw0 = EOFF(cs, r0);
  const int lw1 = EOFF(cs, r0 + 32);

  int ksw[4];
#pragma unroll
  for (int kk = 0; kk < 4; ++kk) ksw[kk] = EOFF(2 * kk + g2, jsub * 32 + l31);
  int vsw0[2], vsw1[2];
#pragma unroll
  for (int J = 0; J < 2; ++J) {
    int c = jsub * 4 + J * 2 + g2;
    vsw0[J] = EOFF(c, l31);
    vsw1[J] = EOFF(c, l31 + 32);
  }
#undef EOFF

  // Q fragments: B-frag col i=l31, d = 16*kk + 8*g2 + e
  bf16x8 q[4];
#pragma unroll
  for (int kk = 0; kk < 4; ++kk)
    q[kk] = *reinterpret_cast<const bf16x8*>(qb + (i0w + l31) * HD + kk * 16 + g2 * 8);

  f32x16 acc0 = {}, acc1 = {};
  f32x16 sO;
  float l_r = 0.f;

  // prologue: stage K(0) into kbuf[0]
  {
    bf16x8 a = *reinterpret_cast<const bf16x8*>(kg0);
    bf16x8 c = *reinterpret_cast<const bf16x8*>(kg1);
    *reinterpret_cast<bf16x8*>(&smem.kv.k[0][lw0]) = a;
    *reinterpret_cast<bf16x8*>(&smem.kv.k[0][lw1]) = c;
  }
  asm volatile("s_waitcnt lgkmcnt(0)" ::: "memory");
  __builtin_amdgcn_s_barrier();

  // ---- peeled iteration 0: QK(0) only; stage K(1), V(0) ----
  {
    bf16x8 kr0 = *reinterpret_cast<const bf16x8*>(kg0 + 64 * HD);
    bf16x8 kr1 = *reinterpret_cast<const bf16x8*>(kg1 + 64 * HD);
    bf16x8 vr0 = *reinterpret_cast<const bf16x8*>(vg0);
    bf16x8 vr1 = *reinterpret_cast<const bf16x8*>(vg1);
    const bf16* kc = smem.kv.k[0];
    f32x16 s = {};
    __builtin_amdgcn_s_setprio(1);
#pragma unroll
    for (int kk = 0; kk < 4; ++kk) {
      bf16x8 kf = *reinterpret_cast<const bf16x8*>(kc + ksw[kk]);
      s = MFMA32(kf, q[kk], s);
    }
    __builtin_amdgcn_s_setprio(0);
    *reinterpret_cast<bf16x8*>(&smem.kv.k[1][lw0]) = kr0;
    *reinterpret_cast<bf16x8*>(&smem.kv.k[1][lw1]) = kr1;
    *reinterpret_cast<bf16x8*>(&smem.kv.v[0][lw0]) = vr0;
    *reinterpret_cast<bf16x8*>(&smem.kv.v[0][lw1]) = vr1;
    asm volatile("s_waitcnt lgkmcnt(0)" ::: "memory");
    __builtin_amdgcn_s_barrier();
    sO = s;
  }

  // ---- main loop: iteration t does softmax(t-1), QK(t), PV(t-1) ----
  for (int t = 1; t < 36; ++t) {
    bf16x8 kr0, kr1;
    if (t < 35) {  // K(t+1) global prefetch
      kr0 = *reinterpret_cast<const bf16x8*>(kg0 + (t + 1) * (64 * HD));
      kr1 = *reinterpret_cast<const bf16x8*>(kg1 + (t + 1) * (64 * HD));
    }
    bf16x8 vr0 = *reinterpret_cast<const bf16x8*>(vg0 + t * 64);  // V(t)
    bf16x8 vr1 = *reinterpret_cast<const bf16x8*>(vg1 + t * 64);

    const bf16* kc = smem.kv.k[t & 1];        // K(t)
    const bf16* vcp = smem.kv.v[(t - 1) & 1]; // V(t-1)

    bf16x8 kf[4], vf0[2], vf1[2];
#pragma unroll
    for (int kk = 0; kk < 4; ++kk)
      kf[kk] = *reinterpret_cast<const bf16x8*>(kc + ksw[kk]);
#pragma unroll
    for (int J = 0; J < 2; ++J) {
      vf0[J] = *reinterpret_cast<const bf16x8*>(vcp + vsw0[J]);
      vf1[J] = *reinterpret_cast<const bf16x8*>(vcp + vsw1[J]);
    }

    // softmax of s(t-1) — VALU, independent of this tile's ds_reads/MFMAs
    u32 P[8];
    float la = 0.f, lb = 0.f;
#pragma unroll
    for (int m = 0; m < 8; ++m) {
      float e0 = fexp2(sO[2 * m]);
      float e1 = fexp2(sO[2 * m + 1]);
      la += e0;
      lb += e1;
      u32 pk;
      asm("v_cvt_pk_bf16_f32 %0, %1, %2" : "=v"(pk) : "v"(e0), "v"(e1));
      P[m] = pk;
    }
    l_r += la + lb;
    bf16x8 pf[2];
#pragma unroll
    for (int J = 0; J < 2; ++J) {
      u32 w0 = P[4 * J], w2 = P[4 * J + 2];
      asm("v_permlane32_swap_b32 %0, %1" : "+v"(w0), "+v"(w2));
      u32 w1 = P[4 * J + 1], w3 = P[4 * J + 3];
      asm("v_permlane32_swap_b32 %0, %1" : "+v"(w1), "+v"(w3));
      i32x4 wv;
      wv[0] = (int)w0; wv[1] = (int)w1; wv[2] = (int)w2; wv[3] = (int)w3;
      pf[J] = __builtin_bit_cast(bf16x8, wv);
    }

    // 3 independent MFMA chains: QK(t) [4-dep], PV acc0 [2-dep], PV acc1 [2-dep]
    f32x16 s = {};
    __builtin_amdgcn_s_setprio(1);
#pragma unroll
    for (int kk = 0; kk < 4; ++kk) s = MFMA32(kf[kk], q[kk], s);
#pragma unroll
    for (int J = 0; J < 2; ++J) {
      acc0 = MFMA32(vf0[J], pf[J], acc0);
      acc1 = MFMA32(vf1[J], pf[J], acc1);
    }
    __builtin_amdgcn_s_setprio(0);

    // staged writes: K(t+1) -> kbuf[(t+1)&1], V(t) -> vbuf[t&1]
    if (t < 35) {
      *reinterpret_cast<bf16x8*>(&smem.kv.k[(t + 1) & 1][lw0]) = kr0;
      *reinterpret_cast<bf16x8*>(&smem.kv.k[(t + 1) & 1][lw1]) = kr1;
    }
    *reinterpret_cast<bf16x8*>(&smem.kv.v[t & 1][lw0]) = vr0;
    *reinterpret_cast<bf16x8*>(&smem.kv.v[t & 1][lw1]) = vr1;
    asm volatile("s_waitcnt lgkmcnt(0)" ::: "memory");
    __builtin_amdgcn_s_barrier();
    sO = s;
  }

  // ---- epilogue: softmax(35) + PV(35) from vbuf[1] ----
  {
    u32 P[8];
    float la = 0.f, lb = 0.f;
#pragma unroll
    for (int m = 0; m < 8; ++m) {
      float e0 = fexp2(sO[2 * m]);
      float e1 = fexp2(sO[2 * m + 1]);
      la += e0;
      lb += e1;
      u32 pk;
      asm("v_cvt_pk_bf16_f32 %0, %1, %2" : "=v"(pk) : "v"(e0), "v"(e1));
      P[m] = pk;
    }
    l_r += la + lb;
    const bf16* vcp = smem.kv.v[1];
#pragma unroll
    for (int J = 0; J < 2; ++J) {
      u32 w0 = P[4 * J], w2 = P[4 * J + 2];
      asm("v_permlane32_swap_b32 %0, %1" : "+v"(w0), "+v"(w2));
      u32 w1 = P[4 * J + 1], w3 = P[4 * J + 3];
      asm("v_permlane32_swap_b32 %0, %1" : "+v"(w1), "+v"(w3));
      i32x4 wv;
      wv[0] = (int)w0; wv[1] = (int)w1; wv[2] = (int)w2; wv[3] = (int)w3;
      bf16x8 pf = __builtin_bit_cast(bf16x8, wv);
      bf16x8 v0 = *reinterpret_cast<const bf16x8*>(vcp + vsw0[J]);
      bf16x8 v1 = *reinterpret_cast<const bf16x8*>(vcp + vsw1[J]);
      acc0 = MFMA32(v0, pf, acc0);
      acc1 = MFMA32(v1, pf, acc1);
    }
  }

  // merge jsub halves: plain add (zero-max => no rescale)
  __builtin_amdgcn_s_barrier();
  if (jsub == 1) {
    float* mb = smem.m[ig][lane];
#pragma unroll
    for (int e = 0; e < 16; ++e) { mb[e] = acc0[e]; mb[16 + e] = acc1[e]; }
    mb[32] = l_r;
  }
  __syncthreads();
  if (jsub == 0) {
    const float* mb = smem.m[ig][lane];
#pragma unroll
    for (int e = 0; e < 16; ++e) { acc0[e] += mb[e]; acc1[e] += mb[16 + e]; }
    l_r += mb[32];
    l_r += __shfl_xor(l_r, 32);
    const float inv = 1.0f / l_r;
    bf16* ob = att + ((size_t)(b * NHW) + i0w + l31) * NC + n * HD;
#pragma unroll
    for (int rq = 0; rq < 4; ++rq) {
      bf16x4 o0, o1;
#pragma unroll
      for (int c = 0; c < 4; ++c) {
        o0[c] = (bf16)(acc0[rq * 4 + c] * inv);
        o1[c] = (bf16)(acc1[rq * 4 + c] * inv);
      }
      *reinterpret_cast<bf16x4*>(ob + 8 * rq + 4 * g2) = o0;
      *reinterpret_cast<bf16x4*>(ob + 32 + 8 * rq + 4 * g2) = o1;
    }
  }
}

// ---------------- proj GEMM + bias + residual ----------------
__global__ __launch_bounds__(256) void k_proj(const bf16* __restrict__ att,
                                              const bf16* __restrict__ wp,
                                              const float* __restrict__ pb,
                                              const float* __restrict__ x,
                                              float* __restrict__ out) {
  int b = blockIdx.z;
  int i_base = blockIdx.x * 128;
  int o_base = blockIdx.y * 128;
  int t = threadIdx.x;
  int lane = t & 63, wid = t >> 6;
  int wm = (wid >> 1) * 64, wn = (wid & 1) * 64;
  int l15 = lane & 15, g = lane >> 4;
  const bf16* ab = wp + (o_base + wm + l15) * NC + g * 8;
  const bf16* bb = att + (b * NHW + i_base + wn + l15) * NC + g * 8;
  f32x4 acc[4][4] = {};
#pragma unroll 2
  for (int kc = 0; kc < 8; ++kc) {
    bf16x8 af[4], bf[4];
#pragma unroll
    for (int mf = 0; mf < 4; ++mf)
      af[mf] = *reinterpret_cast<const bf16x8*>(ab + mf * 16 * NC + kc * 32);
#pragma unroll
    for (int nf = 0; nf < 4; ++nf)
      bf[nf] = *reinterpret_cast<const bf16x8*>(bb + nf * 16 * NC + kc * 32);
#pragma unroll
    for (int mf = 0; mf < 4; ++mf)
#pragma unroll
      for (int nf = 0; nf < 4; ++nf)
        acc[mf][nf] = MFMA16(af[mf], bf[nf], acc[mf][nf]);
  }
  int orow0 = o_base + wm + g * 4;
#pragma unroll
  for (int mf = 0; mf < 4; ++mf)
#pragma unroll
    for (int r = 0; r < 4; ++r) {
      int o = orow0 + mf * 16 + r;
      float bias = pb[o];
      const float* xr = x + (b * NC + o) * NHW + i_base + wn;
      float* orow = out + (b * NC + o) * NHW + i_base + wn;
#pragma unroll
      for (int nf = 0; nf < 4; ++nf) {
        int i = nf * 16 + l15;
        orow[i] = acc[mf][nf][r] + bias + xr[i];
      }
    }
}

extern "C" void kernel_launch(void* const* d_in, const int* in_sizes, int n_in,
                              void* d_out, int out_size, void* d_ws, size_t ws_size,
                              hipStream_t stream) {
  const float* x    = (const float*)d_in[0];
  const float* gnw  = (const float*)d_in[1];
  const float* gnb  = (const float*)d_in[2];
  const float* qkvw = (const float*)d_in[3];
  const float* qkvb = (const float*)d_in[4];
  const float* pw   = (const float*)d_in[5];
  const float* pb   = (const float*)d_in[6];
  float* out = (float*)d_out;

  bf16* ws = (bf16*)d_ws;
  const size_t NE = (size_t)NB * NHW * NC;
  bf16* xnt = ws;
  bf16* qt  = ws + NE;
  bf16* kt  = ws + 2 * NE;
  bf16* vv  = ws + 3 * NE;
  bf16* att = ws + 4 * NE;
  bf16* wqb = ws + 5 * NE;
  bf16* wpb = wqb + 768 * 256;

  k_pre<<<1024, 256, 0, stream>>>(x, gnw, gnb, qkvw, pw, xnt, wqb, wpb);
  k_qkv<<<dim3(18, 6, NB), 256, 0, stream>>>(xnt, wqb, qkvb, qt, kt, vv);
  k_attn<<<1152, 256, 0, stream>>>(qt, kt, vv, att);
  k_proj<<<dim3(18, 2, NB), 256, 0, stream>>>(att, wpb, pb, x, out);
}

// Round 13
// 143.658 us; speedup vs baseline: 1.0407x; 1.0407x over previous
//
#include <hip/hip_runtime.h>
#include <hip/hip_bf16.h>
#include <math.h>

#define NB 8
#define NC 256
#define NHW 2304
#define NH 4
#define HD 64
#define CPG 8
#define GN_EPS 1e-5f

typedef __bf16 bf16;
typedef __bf16 bf16x4 __attribute__((ext_vector_type(4)));
typedef __bf16 bf16x8 __attribute__((ext_vector_type(8)));
typedef float f32x4 __attribute__((ext_vector_type(4)));
typedef float f32x16 __attribute__((ext_vector_type(16)));
typedef int i32x4 __attribute__((ext_vector_type(4)));
typedef unsigned int u32;

#define MFMA16(a, b, c) __builtin_amdgcn_mfma_f32_16x16x32_bf16(a, b, c, 0, 0, 0)
#define MFMA32(a, b, c) __builtin_amdgcn_mfma_f32_32x32x16_bf16(a, b, c, 0, 0, 0)

// fast 2^x: raw v_exp_f32 (exact for our |x| <~ 40 range)
__device__ __forceinline__ float fexp2(float x) {
  float r;
  asm("v_exp_f32 %0, %1" : "=v"(r) : "v"(x));
  return r;
}

// ---------------- fused: weight fp32->bf16 (blocks 0..767) + GroupNorm ------
// GN single-pass: block = (b,g); thread holds its 8ch x 9pos slice (72 f32)
// in registers -> x read ONCE.
__global__ __launch_bounds__(256) void k_pre(const float* __restrict__ x,
                                             const float* __restrict__ gw,
                                             const float* __restrict__ gb,
                                             const float* __restrict__ qw,
                                             const float* __restrict__ pw,
                                             bf16* __restrict__ xnt,
                                             bf16* __restrict__ wq,
                                             bf16* __restrict__ wp) {
  int t = threadIdx.x;
  if (blockIdx.x < 768) {
    int i = blockIdx.x * 256 + t;
    wq[i] = (bf16)qw[i];
    if (i < NC * NC) wp[i] = (bf16)pw[i];
    return;
  }
  int bid = blockIdx.x - 768;
  int b = bid >> 5;
  int g = bid & 31;
  int c0 = g * CPG;
  const float* xb = x + (b * NC + c0) * NHW;
  float v[CPG][9];
  float s = 0.f, s2 = 0.f;
#pragma unroll
  for (int cc = 0; cc < CPG; ++cc)
#pragma unroll
    for (int k = 0; k < 9; ++k) {
      float val = xb[cc * NHW + k * 256 + t];
      v[cc][k] = val;
      s += val;
      s2 += val * val;
    }
#pragma unroll
  for (int m = 1; m < 64; m <<= 1) {
    s += __shfl_xor(s, m);
    s2 += __shfl_xor(s2, m);
  }
  __shared__ float red[8];
  int wid = t >> 6;
  if ((t & 63) == 0) { red[wid] = s; red[4 + wid] = s2; }
  __syncthreads();
  s = red[0] + red[1] + red[2] + red[3];
  s2 = red[4] + red[5] + red[6] + red[7];
  const float inv_n = 1.0f / (CPG * NHW);
  float mean = s * inv_n;
  float var = s2 * inv_n - mean * mean;
  float rsq = rsqrtf(var + GN_EPS);
  float ka[CPG], kb[CPG];
#pragma unroll
  for (int cc = 0; cc < CPG; ++cc) {
    float wv = gw[c0 + cc];
    ka[cc] = wv * rsq;
    kb[cc] = gb[c0 + cc] - mean * rsq * wv;
  }
  bf16* dst = xnt + b * NHW * NC + c0;
#pragma unroll
  for (int k = 0; k < 9; ++k) {
    bf16x8 o;
#pragma unroll
    for (int cc = 0; cc < CPG; ++cc)
      o[cc] = (bf16)(v[cc][k] * ka[cc] + kb[cc]);
    *reinterpret_cast<bf16x8*>(dst + (k * 256 + t) * NC) = o;
  }
}

// ---------------- QKV GEMM: M=hw(i), N=768(o), K=256(c) ----------------
__global__ __launch_bounds__(256) void k_qkv(const bf16* __restrict__ xnt,
                                             const bf16* __restrict__ wq,
                                             const float* __restrict__ qkvb,
                                             bf16* __restrict__ qt,
                                             bf16* __restrict__ kt,
                                             bf16* __restrict__ vv) {
  int b = blockIdx.z;
  int i_base = blockIdx.x * 128;
  int o_base = blockIdx.y * 128;
  int t = threadIdx.x;
  int lane = t & 63, wid = t >> 6;
  int wm = (wid >> 1) * 64, wn = (wid & 1) * 64;
  int l15 = lane & 15, g = lane >> 4;
  const bool qk = (o_base < 512);
  const bf16* ab;
  const bf16* bb;
  if (qk) {
    ab = wq + (o_base + wm + l15) * NC + g * 8;
    bb = xnt + ((size_t)b * NHW + i_base + wn + l15) * NC + g * 8;
  } else {
    ab = xnt + ((size_t)b * NHW + i_base + wm + l15) * NC + g * 8;
    bb = wq + (o_base + wn + l15) * NC + g * 8;
  }
  f32x4 acc[4][4] = {};
#pragma unroll 2
  for (int kc = 0; kc < 8; ++kc) {
    bf16x8 af[4], bf[4];
#pragma unroll
    for (int mf = 0; mf < 4; ++mf)
      af[mf] = *reinterpret_cast<const bf16x8*>(ab + mf * 16 * NC + kc * 32);
#pragma unroll
    for (int nf = 0; nf < 4; ++nf)
      bf[nf] = *reinterpret_cast<const bf16x8*>(bb + nf * 16 * NC + kc * 32);
#pragma unroll
    for (int mf = 0; mf < 4; ++mf)
#pragma unroll
      for (int nf = 0; nf < 4; ++nf)
        acc[mf][nf] = MFMA16(af[mf], bf[nf], acc[mf][nf]);
  }
  if (qk) {
    const float qscale = 0.125f * 1.4426950408889634f;
#pragma unroll
    for (int mf = 0; mf < 4; ++mf) {
      int o0 = o_base + wm + mf * 16 + g * 4;  // rows o0..o0+3
      f32x4 b4 = *reinterpret_cast<const f32x4*>(qkvb + o0);
      bool isQ = (o0 < 256);
      float sc = isQ ? qscale : 1.0f;
      int oo = isQ ? o0 : o0 - 256;
      bf16* base = (isQ ? qt : kt) +
                   ((size_t)(b * NH + (oo >> 6)) * NHW) * HD + (oo & 63);
#pragma unroll
      for (int nf = 0; nf < 4; ++nf) {
        int i = i_base + wn + nf * 16 + l15;
        bf16x4 w;
#pragma unroll
        for (int r = 0; r < 4; ++r)
          w[r] = (bf16)((acc[mf][nf][r] + b4[r]) * sc);
        *reinterpret_cast<bf16x4*>(base + (size_t)i * HD) = w;
      }
    }
  } else {
#pragma unroll
    for (int nf = 0; nf < 4; ++nf) {
      int og = o_base + wn + nf * 16 + l15;  // 512..767
      float bias = qkvb[og];
      int o2 = og - 512;
      bf16* dp = vv + ((size_t)(b * NH + (o2 >> 6)) * HD + (o2 & 63)) * NHW +
                 i_base + wm + g * 4;
#pragma unroll
      for (int mf = 0; mf < 4; ++mf) {
        bf16x4 w;
#pragma unroll
        for (int r = 0; r < 4; ++r) w[r] = (bf16)(acc[mf][nf][r] + bias);
        *reinterpret_cast<bf16x4*>(dp + mf * 16) = w;
      }
    }
  }
}

// ---------------- flash attention: 8-wave blocks (occupancy lever) ----------
// Hypothesis: only ~64KB LDS/CU is effectively allocatable -> a 32KB block
// caps residency at 2 blocks/CU. 8 waves/block keeps LDS at 32KB dbuf but
// doubles waves/CU: 2 blocks x 8 = 16 waves/CU (vs r11's 8). Block covers
// 128 i x 64-j tiles: waves = (ig 0..3, jsub 0..1); per-wave inner loop is
// EXACTLY r11's (frag reads, QK 4xMFMA32, zero-max fexp2 softmax,
// permlane P->frags, PV 4xMFMA32, staged write, one lgkm+barrier per tile).
// Staging: 512 thr x 1 K-chunk + 1 V-chunk (16B each) per tile.
// Grid 576 = 8 XCD x 72 (bijective swizzle, 4 heads/XCD -> K/V L2-resident).
// jsub-merge: two-phase through mbuf[4][64][17] aliased over kv LDS.
__global__ __launch_bounds__(512, 4) void k_attn(const bf16* __restrict__ qt,
                                                 const bf16* __restrict__ kt,
                                                 const bf16* __restrict__ vv,
                                                 bf16* __restrict__ att) {
  __shared__ union SM {
    struct { bf16 k[2][4096]; bf16 v[2][4096]; } kv;  // 32 KB
    float m[4][64][17];                                // 17.4 KB (epilogue)
  } smem;

  const int tid = threadIdx.x;
  const int wid = tid >> 6, lane = tid & 63;
  const int l31 = lane & 31, g2 = lane >> 5;
  const int ig = wid & 3, jsub = wid >> 2;

  // bijective XCD swizzle: 576 blocks = 8 XCD x 72; each XCD gets 4 heads
  const int bid = blockIdx.x;
  const int wg = (bid & 7) * 72 + (bid >> 3);
  const int bh = wg / 18, it = wg % 18;
  const int b = bh >> 2, n = bh & 3;
  const int i0w = it * 128 + ig * 32;

  const bf16* qb = qt + (size_t)bh * NHW * HD;
  const bf16* kb = kt + (size_t)bh * NHW * HD;
  const bf16* vb = vv + (size_t)bh * HD * NHW;

  // staging: 512 thr -> (r0 = row 0..63, cs = chunk 0..7), 1 K + 1 V chunk
  const int r0 = tid >> 3, cs = tid & 7;
  const bf16* kg = kb + r0 * HD + cs * 8;
  const bf16* vg = vb + (size_t)r0 * NHW + cs * 8;
#define EOFF(c, row) ((c) * 512 + ((((row) + (c)) & 63) << 3))
  const int lw = EOFF(cs, r0);

  // K fragment offsets: chunk 2kk+g2, rows jsub*32 + l31 (contiguous 512B)
  int ksw[4];
#pragma unroll
  for (int kk = 0; kk < 4; ++kk) ksw[kk] = EOFF(2 * kk + g2, jsub * 32 + l31);
  // V fragment offsets: chunk jsub*4+J*2+g2, rows l31 / l31+32
  int vsw0[2], vsw1[2];
#pragma unroll
  for (int J = 0; J < 2; ++J) {
    int c = jsub * 4 + J * 2 + g2;
    vsw0[J] = EOFF(c, l31);
    vsw1[J] = EOFF(c, l31 + 32);
  }
#undef EOFF

  // Q fragments: B-frag col i=l31, d = 16*kk + 8*g2 + e
  bf16x8 q[4];
#pragma unroll
  for (int kk = 0; kk < 4; ++kk)
    q[kk] = *reinterpret_cast<const bf16x8*>(qb + (i0w + l31) * HD + kk * 16 + g2 * 8);

  f32x16 acc0 = {}, acc1 = {};
  float l_r = 0.f;

  // prologue: stage tile 0 into buf 0
  {
    bf16x8 a = *reinterpret_cast<const bf16x8*>(kg);
    bf16x8 d = *reinterpret_cast<const bf16x8*>(vg);
    *reinterpret_cast<bf16x8*>(&smem.kv.k[0][lw]) = a;
    *reinterpret_cast<bf16x8*>(&smem.kv.v[0][lw]) = d;
  }
  asm volatile("s_waitcnt lgkmcnt(0)" ::: "memory");
  __builtin_amdgcn_s_barrier();

  for (int t = 0; t < 36; ++t) {
    const int cur = t & 1;
    bf16x8 kr, vr;
    if (t < 35) {  // issue next-tile global loads early (hide under compute)
      kr = *reinterpret_cast<const bf16x8*>(kg + (t + 1) * (64 * HD));
      vr = *reinterpret_cast<const bf16x8*>(vg + (t + 1) * 64);
    }
    const bf16* kc = smem.kv.k[cur];
    const bf16* vc = smem.kv.v[cur];

    // S^T = K . Q^T over this wave's 32-j subtile
    f32x16 s = {};
    __builtin_amdgcn_s_setprio(1);
#pragma unroll
    for (int kk = 0; kk < 4; ++kk) {
      bf16x8 kf = *reinterpret_cast<const bf16x8*>(kc + ksw[kk]);
      s = MFMA32(kf, q[kk], s);
    }
    __builtin_amdgcn_s_setprio(0);

    // zero-max softmax: P = 2^s (raw v_exp_f32), lane-local partial sum
    u32 P[8];
    float la = 0.f, lb = 0.f;
#pragma unroll
    for (int m = 0; m < 8; ++m) {
      float e0 = fexp2(s[2 * m]);
      float e1 = fexp2(s[2 * m + 1]);
      la += e0;
      lb += e1;
      u32 pk;
      asm("v_cvt_pk_bf16_f32 %0, %1, %2" : "=v"(pk) : "v"(e0), "v"(e1));
      P[m] = pk;
    }
    l_r += la + lb;

    // PV: build B-frags in regs via permlane32_swap, accumulate O^T
#pragma unroll
    for (int J = 0; J < 2; ++J) {
      u32 w0 = P[4 * J], w2 = P[4 * J + 2];
      asm("v_permlane32_swap_b32 %0, %1" : "+v"(w0), "+v"(w2));
      u32 w1 = P[4 * J + 1], w3 = P[4 * J + 3];
      asm("v_permlane32_swap_b32 %0, %1" : "+v"(w1), "+v"(w3));
      i32x4 wv;
      wv[0] = (int)w0; wv[1] = (int)w1; wv[2] = (int)w2; wv[3] = (int)w3;
      bf16x8 pf = __builtin_bit_cast(bf16x8, wv);
      bf16x8 v0 = *reinterpret_cast<const bf16x8*>(vc + vsw0[J]);
      bf16x8 v1 = *reinterpret_cast<const bf16x8*>(vc + vsw1[J]);
      __builtin_amdgcn_s_setprio(1);
      acc0 = MFMA32(v0, pf, acc0);
      acc1 = MFMA32(v1, pf, acc1);
      __builtin_amdgcn_s_setprio(0);
    }

    if (t < 35) {  // write staged regs into other buffer
      const int nb = cur ^ 1;
      *reinterpret_cast<bf16x8*>(&smem.kv.k[nb][lw]) = kr;
      *reinterpret_cast<bf16x8*>(&smem.kv.v[nb][lw]) = vr;
    }
    asm volatile("s_waitcnt lgkmcnt(0)" ::: "memory");
    __builtin_amdgcn_s_barrier();
  }

  // merge jsub halves (plain add, zero-max => no rescale), two phases
  if (jsub == 1) {
    float* mb = smem.m[ig][lane];
#pragma unroll
    for (int e = 0; e < 16; ++e) mb[e] = acc0[e];
    mb[16] = l_r;
  }
  __syncthreads();
  if (jsub == 0) {
    const float* mb = smem.m[ig][lane];
#pragma unroll
    for (int e = 0; e < 16; ++e) acc0[e] += mb[e];
    l_r += mb[16];
  }
  __syncthreads();
  if (jsub == 1) {
    float* mb = smem.m[ig][lane];
#pragma unroll
    for (int e = 0; e < 16; ++e) mb[e] = acc1[e];
  }
  __syncthreads();
  if (jsub == 0) {
    const float* mb = smem.m[ig][lane];
#pragma unroll
    for (int e = 0; e < 16; ++e) acc1[e] += mb[e];
    l_r += __shfl_xor(l_r, 32);
    const float inv = 1.0f / l_r;
    bf16* ob = att + ((size_t)(b * NHW) + i0w + l31) * NC + n * HD;
#pragma unroll
    for (int rq = 0; rq < 4; ++rq) {
      bf16x4 o0, o1;
#pragma unroll
      for (int c = 0; c < 4; ++c) {
        o0[c] = (bf16)(acc0[rq * 4 + c] * inv);
        o1[c] = (bf16)(acc1[rq * 4 + c] * inv);
      }
      *reinterpret_cast<bf16x4*>(ob + 8 * rq + 4 * g2) = o0;
      *reinterpret_cast<bf16x4*>(ob + 32 + 8 * rq + 4 * g2) = o1;
    }
  }
}

// ---------------- proj GEMM + bias + residual ----------------
__global__ __launch_bounds__(256) void k_proj(const bf16* __restrict__ att,
                                              const bf16* __restrict__ wp,
                                              const float* __restrict__ pb,
                                              const float* __restrict__ x,
                                              float* __restrict__ out) {
  int b = blockIdx.z;
  int i_base = blockIdx.x * 128;
  int o_base = blockIdx.y * 128;
  int t = threadIdx.x;
  int lane = t & 63, wid = t >> 6;
  int wm = (wid >> 1) * 64, wn = (wid & 1) * 64;
  int l15 = lane & 15, g = lane >> 4;
  const bf16* ab = wp + (o_base + wm + l15) * NC + g * 8;
  const bf16* bb = att + (b * NHW + i_base + wn + l15) * NC + g * 8;
  f32x4 acc[4][4] = {};
#pragma unroll 2
  for (int kc = 0; kc < 8; ++kc) {
    bf16x8 af[4], bf[4];
#pragma unroll
    for (int mf = 0; mf < 4; ++mf)
      af[mf] = *reinterpret_cast<const bf16x8*>(ab + mf * 16 * NC + kc * 32);
#pragma unroll
    for (int nf = 0; nf < 4; ++nf)
      bf[nf] = *reinterpret_cast<const bf16x8*>(bb + nf * 16 * NC + kc * 32);
#pragma unroll
    for (int mf = 0; mf < 4; ++mf)
#pragma unroll
      for (int nf = 0; nf < 4; ++nf)
        acc[mf][nf] = MFMA16(af[mf], bf[nf], acc[mf][nf]);
  }
  int orow0 = o_base + wm + g * 4;
#pragma unroll
  for (int mf = 0; mf < 4; ++mf)
#pragma unroll
    for (int r = 0; r < 4; ++r) {
      int o = orow0 + mf * 16 + r;
      float bias = pb[o];
      const float* xr = x + (b * NC + o) * NHW + i_base + wn;
      float* orow = out + (b * NC + o) * NHW + i_base + wn;
#pragma unroll
      for (int nf = 0; nf < 4; ++nf) {
        int i = nf * 16 + l15;
        orow[i] = acc[mf][nf][r] + bias + xr[i];
      }
    }
}

extern "C" void kernel_launch(void* const* d_in, const int* in_sizes, int n_in,
                              void* d_out, int out_size, void* d_ws, size_t ws_size,
                              hipStream_t stream) {
  const float* x    = (const float*)d_in[0];
  const float* gnw  = (const float*)d_in[1];
  const float* gnb  = (const float*)d_in[2];
  const float* qkvw = (const float*)d_in[3];
  const float* qkvb = (const float*)d_in[4];
  const float* pw   = (const float*)d_in[5];
  const float* pb   = (const float*)d_in[6];
  float* out = (float*)d_out;

  bf16* ws = (bf16*)d_ws;
  const size_t NE = (size_t)NB * NHW * NC;
  bf16* xnt = ws;
  bf16* qt  = ws + NE;
  bf16* kt  = ws + 2 * NE;
  bf16* vv  = ws + 3 * NE;
  bf16* att = ws + 4 * NE;
  bf16* wqb = ws + 5 * NE;
  bf16* wpb = wqb + 768 * 256;

  k_pre<<<1024, 256, 0, stream>>>(x, gnw, gnb, qkvw, pw, xnt, wqb, wpb);
  k_qkv<<<dim3(18, 6, NB), 256, 0, stream>>>(xnt, wqb, qkvb, qt, kt, vv);
  k_attn<<<576, 512, 0, stream>>>(qt, kt, vv, att);
  k_proj<<<dim3(18, 2, NB), 256, 0, stream>>>(att, wpb, pb, x, out);
}